// Round 1
// baseline (605.169 us; speedup 1.0000x reference)
//
#include <hip/hip_runtime.h>

#define N_NODES 20000
#define N_EDGES 320000
#define SEQ 8

typedef __attribute__((ext_vector_type(8))) short bf16x8;
typedef __attribute__((ext_vector_type(4))) float floatx4;
typedef const unsigned int __attribute__((address_space(1)))* gas_u32;
typedef unsigned int __attribute__((address_space(3)))* las_u32;

__device__ __forceinline__ unsigned short f2bf(float f) {
  unsigned int u = __builtin_bit_cast(unsigned int, f);
  return (unsigned short)((u + 0x7fffu + ((u >> 16) & 1u)) >> 16);
}
__device__ __forceinline__ float bflo(unsigned int u) {
  return __builtin_bit_cast(float, u << 16);
}
__device__ __forceinline__ float bfhi(unsigned int u) {
  return __builtin_bit_cast(float, u & 0xffff0000u);
}
__device__ __forceinline__ float sigf(float x) { return 1.f / (1.f + __expf(-x)); }

// async global->LDS, 16B per lane; LDS dest = wave-uniform base + lane*16
__device__ __forceinline__ void gl_lds16(const void* g, void* l) {
  auto gp = (gas_u32)g;
  auto lp = (las_u32)(unsigned int)(unsigned long long)l;  // strip aperture
  __builtin_amdgcn_global_load_lds(gp, lp, 16, 0, 0);
}

// ---------------- setup kernels ----------------

// deg/counts init + weight transpose/convert. WiT[n][k]=Wi[k][n] (256x256).
// W1T/W2T gate-interleaved: n'=4j+gate, orig=gate*128+j; W1 = Wc rows 0..127,
// W2 = Wc rows 128..255. bcp = b_cell permuted.
__global__ void k_prologue(const float* __restrict__ Wi,
                           const float* __restrict__ Wc,
                           const float* __restrict__ bc,
                           unsigned short* __restrict__ WiT,
                           unsigned short* __restrict__ W1T,
                           unsigned short* __restrict__ W2T,
                           float* __restrict__ bcp,
                           float* __restrict__ deg, int* __restrict__ counts) {
  int idx = blockIdx.x * 256 + threadIdx.x;  // 0..131071
  if (idx < N_NODES) { deg[idx] = 1.0f; counts[idx] = 0; }
  if (idx < 65536) {
    int n = idx >> 8, k = idx & 255;
    WiT[n * 256 + k] = f2bf(Wi[k * 256 + n]);
  }
  if (idx < 512) bcp[idx] = bc[((idx & 3) << 7) | (idx >> 2)];
  int n2 = idx >> 8, k2 = idx & 255;  // n2 0..511
  if (k2 < 128) {
    int orig = ((n2 & 3) << 7) | (n2 >> 2);
    W1T[n2 * 128 + k2] = f2bf(Wc[k2 * 512 + orig]);
    W2T[n2 * 128 + k2] = f2bf(Wc[(k2 + 128) * 512 + orig]);
  }
}

__global__ void k_deg(const int* __restrict__ ei, const float* __restrict__ ea,
                      float* __restrict__ deg, int* __restrict__ counts) {
  int e = blockIdx.x * 256 + threadIdx.x;
  if (e >= N_EDGES) return;
  int d = ei[N_EDGES + e];
  atomicAdd(&deg[d], ea[e]);
  atomicAdd(&counts[d], 1);
}

// single-block scan: counts -> exclusive row_ptr/cursor; dinv = rsqrt(deg)
__global__ __launch_bounds__(1024) void k_scan(
    const int* __restrict__ counts, const float* __restrict__ deg,
    float* __restrict__ dinv, int* __restrict__ row_ptr,
    int* __restrict__ cursor) {
  __shared__ int sm[1024];
  int t = threadIdx.x;
  int base = t * 20;
  int local[20];
  int s = 0;
#pragma unroll
  for (int i = 0; i < 20; ++i) {
    int g = base + i;
    int v = (g < N_NODES) ? counts[g] : 0;
    local[i] = v;
    s += v;
  }
  sm[t] = s;
  __syncthreads();
  for (int o = 1; o < 1024; o <<= 1) {
    int add = (t >= o) ? sm[t - o] : 0;
    __syncthreads();
    sm[t] += add;
    __syncthreads();
  }
  int run = sm[t] - s;  // exclusive prefix of this thread's chunk
#pragma unroll
  for (int i = 0; i < 20; ++i) {
    int g = base + i;
    if (g < N_NODES) {
      row_ptr[g] = run;
      cursor[g] = run;
      dinv[g] = rsqrtf(deg[g]);
    }
    run += local[i];
  }
  if (t == 0) row_ptr[N_NODES] = N_EDGES;
}

// csr packed as int2 {src, bitcast(weight)} -> one 8B uniform load per edge
__global__ void k_fill(const int* __restrict__ ei, const float* __restrict__ ea,
                       const float* __restrict__ dinv, int* __restrict__ cursor,
                       int2* __restrict__ csr) {
  int e = blockIdx.x * 256 + threadIdx.x;
  if (e >= N_EDGES) return;
  int s = ei[e], d = ei[N_EDGES + e];
  int k = atomicAdd(&cursor[d], 1);
  int2 p;
  p.x = s;
  p.y = __builtin_bit_cast(int, dinv[s] * ea[e] * dinv[d]);
  csr[k] = p;
}

// ---------------- aggregation (gather via CSR, one wave per node) -------------
// Edge list is WAVE-UNIFORM: readfirstlane the node id + row range, load the
// packed int2 edge records at uniform addresses (scalar/broadcast path) and
// readfirstlane the payload into SGPRs. No __shfl/ds_bpermute machinery.

// init: gather fp32 h,c -> AhAc rows (256 bf16: cols 0..127 Ah, 128..255 Ac)
__global__ __launch_bounds__(256) void k_agg_init(
    const float* __restrict__ h, const float* __restrict__ c,
    unsigned int* __restrict__ AhAc_u, const float* __restrict__ dinv,
    const int* __restrict__ row_ptr, const int2* __restrict__ csr) {
  int lane = threadIdx.x & 63;
  int wid =
      __builtin_amdgcn_readfirstlane((blockIdx.x * 256 + threadIdx.x) >> 6);
  if (wid >= N_NODES) return;
  float di = dinv[wid], dd = di * di;
  const float4* xb = (lane < 32) ? (const float4*)h : (const float4*)c;
  int lcol = lane & 31;
  float4 a = xb[(size_t)wid * 32 + lcol];
  float s0 = a.x * dd, s1 = a.y * dd, s2 = a.z * dd, s3 = a.w * dd;
  int e0 = __builtin_amdgcn_readfirstlane(row_ptr[wid]);
  int end = __builtin_amdgcn_readfirstlane(row_ptr[wid + 1]);

#define EDGE_I(P)                                                        \
  {                                                                      \
    int sidx = __builtin_amdgcn_readfirstlane((P).x);                    \
    float wv = __builtin_bit_cast(                                       \
        float, __builtin_amdgcn_readfirstlane((P).y));                   \
    float4 v = xb[(size_t)sidx * 32 + lcol];                             \
    s0 += v.x * wv; s1 += v.y * wv; s2 += v.z * wv; s3 += v.w * wv;      \
  }

  int j = e0;
  for (; j + 4 <= end; j += 4) {
    int2 p0 = csr[j], p1 = csr[j + 1], p2 = csr[j + 2], p3 = csr[j + 3];
    EDGE_I(p0) EDGE_I(p1) EDGE_I(p2) EDGE_I(p3)
  }
  for (; j < end; ++j) {
    int2 p = csr[j];
    EDGE_I(p)
  }
#undef EDGE_I
  uint2 o;
  o.x = (unsigned int)f2bf(s0) | ((unsigned int)f2bf(s1) << 16);
  o.y = (unsigned int)f2bf(s2) | ((unsigned int)f2bf(s3) << 16);
  ((uint2*)AhAc_u)[(size_t)wid * 64 + lane] = o;
}

// step: gather hbf rows (128 bf16) -> compact Aht rows
__global__ __launch_bounds__(256) void k_agg_step(
    const unsigned int* __restrict__ hbf_u, unsigned int* __restrict__ Aht_u,
    const float* __restrict__ dinv, const int* __restrict__ row_ptr,
    const int2* __restrict__ csr) {
  int lane = threadIdx.x & 63;
  int wid =
      __builtin_amdgcn_readfirstlane((blockIdx.x * 256 + threadIdx.x) >> 6);
  if (wid >= N_NODES) return;
  float di = dinv[wid], dd = di * di;
  unsigned int a = hbf_u[(size_t)wid * 64 + lane];
  float s0 = bflo(a) * dd, s1 = bfhi(a) * dd;
  int e0 = __builtin_amdgcn_readfirstlane(row_ptr[wid]);
  int end = __builtin_amdgcn_readfirstlane(row_ptr[wid + 1]);

#define EDGE_S(P)                                                        \
  {                                                                      \
    int sidx = __builtin_amdgcn_readfirstlane((P).x);                    \
    float wv = __builtin_bit_cast(                                       \
        float, __builtin_amdgcn_readfirstlane((P).y));                   \
    unsigned int v = hbf_u[(size_t)sidx * 64 + lane];                    \
    s0 += bflo(v) * wv; s1 += bfhi(v) * wv;                              \
  }

  int j = e0;
  for (; j + 4 <= end; j += 4) {
    int2 p0 = csr[j], p1 = csr[j + 1], p2 = csr[j + 2], p3 = csr[j + 3];
    EDGE_S(p0) EDGE_S(p1) EDGE_S(p2) EDGE_S(p3)
  }
  for (; j < end; ++j) {
    int2 p = csr[j];
    EDGE_S(p)
  }
#undef EDGE_S
  Aht_u[(size_t)wid * 64 + lane] =
      (unsigned int)f2bf(s0) | ((unsigned int)f2bf(s1) << 16);
}

// ---------------- bf16 MFMA GEMM with global_load_lds + XOR-swizzled LDS -----
// C[128x128] = A[128xKK](row-stride LDA) @ BT[128 of KK]^T + epilogue.
// K staged 128-wide per barrier round (two 64-wide swizzled buffers) -> one
// vmcnt drain + 2 barriers per 128 of K instead of two drains + 4 barriers.
// EPI 0 (init, KK=256): v += bias[gcol]; elu; col<128 -> hbf else c_cur.
// EPI 1 (Kbuf build, KK=128): Kbuf = v + bcp[gcol]  (gate-interleaved cols).
// EPI 2 (step, KK=128): gates fused; gi..gg = acc + Kbuf (has bias).
template <int EPI, int KK, int LDA>
__global__ __launch_bounds__(256) void k_gemm(
    const unsigned short* __restrict__ A, const unsigned short* __restrict__ BT,
    const float* __restrict__ bias, const float* __restrict__ Kbuf,
    float* __restrict__ c_cur, unsigned short* __restrict__ hbf,
    float* __restrict__ out0) {
  __shared__ __align__(16) union {
    struct {
      unsigned short a[2][128 * 64];
      unsigned short b[2][128 * 64];
    } ab;
    float ep[64 * 132];
  } sm;
  const int M = N_NODES;
  int tid = threadIdx.x;
  int bm0 = blockIdx.x * 128, bn0 = blockIdx.y * 128;
  int wave = tid >> 6, lane = tid & 63;
  int wrow = (wave >> 1) * 64, wcol = (wave & 1) * 64;
  int lr = lane & 15, lq = lane >> 4;
  int key = lr & 7;

  // staging lane roles: 8 lanes/row, 8 rows/wave/call
  int lr8 = lane >> 3, cq = lane & 7;
  int gq8 = (cq ^ lr8) * 8;  // swizzled global chunk offset (shorts)

  floatx4 acc[4][4];
#pragma unroll
  for (int i = 0; i < 4; i++)
#pragma unroll
    for (int j = 0; j < 4; j++) acc[i][j] = (floatx4){0.f, 0.f, 0.f, 0.f};

  for (int k0 = 0; k0 < KK; k0 += 128) {
    if (k0) __syncthreads();
#pragma unroll
    for (int half = 0; half < 2; ++half) {
      int kk = k0 + half * 64;
#pragma unroll
      for (int p = 0; p < 4; ++p) {
        int row = p * 32 + wave * 8;  // wave-uniform base row
        int ra = bm0 + row + lr8;
        if (ra > M - 1) ra = M - 1;  // clamp: junk rows never stored
        gl_lds16(A + (size_t)ra * LDA + kk + gq8, sm.ab.a[half] + row * 64);
        gl_lds16(BT + (size_t)(bn0 + row + lr8) * KK + kk + gq8,
                 sm.ab.b[half] + row * 64);
      }
    }
    __syncthreads();
#pragma unroll
    for (int half = 0; half < 2; ++half) {
#pragma unroll
      for (int ks = 0; ks < 2; ++ks) {
        int q = ks * 4 + lq;
        int slot = (q ^ key) << 3;
        bf16x8 af[4], bfr[4];
#pragma unroll
        for (int mi = 0; mi < 4; mi++)
          af[mi] =
              *(const bf16x8*)(sm.ab.a[half] + (wrow + mi * 16 + lr) * 64 + slot);
#pragma unroll
        for (int ni = 0; ni < 4; ni++)
          bfr[ni] =
              *(const bf16x8*)(sm.ab.b[half] + (wcol + ni * 16 + lr) * 64 + slot);
#pragma unroll
        for (int mi = 0; mi < 4; mi++)
#pragma unroll
          for (int ni = 0; ni < 4; ni++)
            acc[mi][ni] = __builtin_amdgcn_mfma_f32_16x16x32_bf16(
                af[mi], bfr[ni], acc[mi][ni], 0, 0, 0);
      }
    }
  }
  __syncthreads();  // sm.ab dead before epilogue reuse

  if (EPI == 0) {
#pragma unroll
    for (int mi = 0; mi < 4; mi++) {
#pragma unroll
      for (int r = 0; r < 4; r++) {
        int grow = bm0 + wrow + mi * 16 + lq * 4 + r;
        if (grow >= M) continue;
#pragma unroll
        for (int ni = 0; ni < 4; ni++) {
          int gcol = bn0 + wcol + ni * 16 + lr;
          float v = acc[mi][ni][r] + bias[gcol];
          v = (v > 0.f) ? v : expm1f(v);
          if (gcol < 128) hbf[(size_t)grow * 128 + gcol] = f2bf(v);
          else c_cur[(size_t)grow * 128 + gcol - 128] = v;
        }
      }
    }
  } else if (EPI == 1) {
#pragma unroll
    for (int mi = 0; mi < 4; mi++) {
#pragma unroll
      for (int r = 0; r < 4; r++) {
        int grow = bm0 + wrow + mi * 16 + lq * 4 + r;
        if (grow >= M) continue;
#pragma unroll
        for (int ni = 0; ni < 4; ni++) {
          int gcol = bn0 + wcol + ni * 16 + lr;
          out0[(size_t)grow * 512 + gcol] = acc[mi][ni][r] + bias[gcol];
        }
      }
    }
  } else {
    // two 64-row chunks through LDS transpose; fused LSTM gates
#pragma unroll
    for (int hch = 0; hch < 2; ++hch) {
      if ((wrow >> 6) == hch) {
#pragma unroll
        for (int mi = 0; mi < 4; mi++)
#pragma unroll
          for (int r = 0; r < 4; r++) {
            int row_l = mi * 16 + lq * 4 + r;
#pragma unroll
            for (int ni = 0; ni < 4; ni++)
              sm.ep[row_l * 132 + wcol + ni * 16 + lr] = acc[mi][ni][r];
          }
      }
      __syncthreads();
#pragma unroll
      for (int it = 0; it < 8; ++it) {
        int p = tid + it * 256;
        int row_l = p >> 5, j = p & 31;
        int grow = bm0 + hch * 64 + row_l;
        if (grow < M) {
          int jg = (bn0 >> 2) + j;
          const float* eb = sm.ep + row_l * 132 + 4 * j;
          float4 kb = *(const float4*)&Kbuf[(size_t)grow * 512 + bn0 + 4 * j];
          float gi = eb[0] + kb.x;
          float gf = eb[1] + kb.y;
          float go = eb[2] + kb.z;
          float gg = eb[3] + kb.w;
          size_t o = (size_t)grow * 128 + jg;
          float cp = c_cur[o];
          float cn = sigf(gf) * cp + sigf(gi) * tanhf(gg);
          float hn = sigf(go) * tanhf(cn);
          c_cur[o] = cn;
          hbf[o] = f2bf(hn);
          out0[o] = hn;
        }
      }
      __syncthreads();
    }
  }
}

// ---------------- host launcher ----------------
extern "C" void kernel_launch(void* const* d_in, const int* in_sizes, int n_in,
                              void* d_out, int out_size, void* d_ws, size_t ws_size,
                              hipStream_t stream) {
  const float* h  = (const float*)d_in[0];
  const float* c  = (const float*)d_in[1];
  const int*   ei = (const int*)d_in[2];
  const float* ea = (const float*)d_in[3];
  const float* Wi = (const float*)d_in[4];
  const float* bi = (const float*)d_in[5];
  const float* Wc = (const float*)d_in[6];
  const float* bc = (const float*)d_in[7];
  float* out = (float*)d_out;

  char* w = (char*)d_ws;
  size_t off = 0;
  auto alloc = [&](size_t bytes) {
    void* p = w + off;
    off += (bytes + 511) & ~(size_t)511;
    return p;
  };
  float* deg           = (float*)alloc(N_NODES * 4);
  float* dinv          = (float*)alloc(N_NODES * 4);
  int* counts          = (int*)alloc(N_NODES * 4);
  int* cursor          = (int*)alloc(N_NODES * 4);
  int* row_ptr         = (int*)alloc((N_NODES + 1) * 4);
  int2* csr            = (int2*)alloc((size_t)N_EDGES * 8);
  unsigned short* WiT  = (unsigned short*)alloc(256 * 256 * 2);
  unsigned short* W1T  = (unsigned short*)alloc(512 * 128 * 2);
  unsigned short* W2T  = (unsigned short*)alloc(512 * 128 * 2);
  float* bcp           = (float*)alloc(512 * 4);
  unsigned short* AhAc = (unsigned short*)alloc((size_t)N_NODES * 256 * 2);
  unsigned short* Aht  = (unsigned short*)alloc((size_t)N_NODES * 128 * 2);
  unsigned short* hbf  = (unsigned short*)alloc((size_t)N_NODES * 128 * 2);
  float* c_cur         = (float*)alloc((size_t)N_NODES * 128 * 4);
  float* Kbuf          = (float*)alloc((size_t)N_NODES * 512 * 4);

  const int NB_E = (N_EDGES + 255) / 256;  // 1250
  const int NB_AGG = N_NODES * 64 / 256;   // 5000
  const int MB = (N_NODES + 127) / 128;    // 157

  k_prologue<<<512, 256, 0, stream>>>(Wi, Wc, bc, WiT, W1T, W2T, bcp, deg,
                                      counts);
  k_deg<<<NB_E, 256, 0, stream>>>(ei, ea, deg, counts);
  k_scan<<<1, 1024, 0, stream>>>(counts, deg, dinv, row_ptr, cursor);
  k_fill<<<NB_E, 256, 0, stream>>>(ei, ea, dinv, cursor, csr);

  k_agg_init<<<NB_AGG, 256, 0, stream>>>(h, c, (unsigned int*)AhAc, dinv,
                                         row_ptr, csr);
  // states = elu([Ah|Ac]@Wi + bi) -> hbf, c_cur
  k_gemm<0, 256, 256><<<dim3(MB, 2), 256, 0, stream>>>(
      AhAc, WiT, bi, nullptr, c_cur, hbf, nullptr);
  // Kbuf = Ah@W1 + bcp (gate-interleaved), A = AhAc cols 0..127
  k_gemm<1, 128, 256><<<dim3(MB, 4), 256, 0, stream>>>(
      AhAc, W1T, bcp, nullptr, nullptr, nullptr, Kbuf);

  for (int t = 0; t < SEQ; ++t) {
    k_agg_step<<<NB_AGG, 256, 0, stream>>>((unsigned int*)hbf,
                                           (unsigned int*)Aht, dinv, row_ptr,
                                           csr);
    k_gemm<2, 128, 128><<<dim3(MB, 4), 256, 0, stream>>>(
        Aht, W2T, nullptr, Kbuf, c_cur, hbf, out + (size_t)t * N_NODES * 128);
  }
}

// Round 2
// 508.927 us; speedup vs baseline: 1.1891x; 1.1891x over previous
//
#include <hip/hip_runtime.h>

#define N_NODES 20000
#define N_EDGES 320000
#define SEQ 8

typedef __attribute__((ext_vector_type(8))) short bf16x8;
typedef __attribute__((ext_vector_type(4))) float floatx4;
typedef const unsigned int __attribute__((address_space(1)))* gas_u32;
typedef unsigned int __attribute__((address_space(3)))* las_u32;

__device__ __forceinline__ unsigned short f2bf(float f) {
  unsigned int u = __builtin_bit_cast(unsigned int, f);
  return (unsigned short)((u + 0x7fffu + ((u >> 16) & 1u)) >> 16);
}
__device__ __forceinline__ float bflo(unsigned int u) {
  return __builtin_bit_cast(float, u << 16);
}
__device__ __forceinline__ float bfhi(unsigned int u) {
  return __builtin_bit_cast(float, u & 0xffff0000u);
}
__device__ __forceinline__ float sigf(float x) { return 1.f / (1.f + __expf(-x)); }

// async global->LDS, 16B per lane; LDS dest = wave-uniform base + lane*16
__device__ __forceinline__ void gl_lds16(const void* g, void* l) {
  auto gp = (gas_u32)g;
  auto lp = (las_u32)(unsigned int)(unsigned long long)l;  // strip aperture
  __builtin_amdgcn_global_load_lds(gp, lp, 16, 0, 0);
}

// ---------------- setup kernels ----------------

// deg/counts init + weight transpose/convert. WiT[n][k]=Wi[k][n] (256x256).
// WcT combined 512x256 gate-interleaved: n'=4j+gate, orig=gate*128+j;
// k 0..255 spans [W1;W2] (Wc rows 0..255). bcp = b_cell permuted.
__global__ void k_prologue(const float* __restrict__ Wi,
                           const float* __restrict__ Wc,
                           const float* __restrict__ bc,
                           unsigned short* __restrict__ WiT,
                           unsigned short* __restrict__ WcT,
                           float* __restrict__ bcp,
                           float* __restrict__ deg, int* __restrict__ counts) {
  int idx = blockIdx.x * 256 + threadIdx.x;  // 0..131071
  if (idx < N_NODES) { deg[idx] = 1.0f; counts[idx] = 0; }
  if (idx < 65536) {
    int n = idx >> 8, k = idx & 255;
    WiT[n * 256 + k] = f2bf(Wi[k * 256 + n]);
  }
  if (idx < 512) bcp[idx] = bc[((idx & 3) << 7) | (idx >> 2)];
  int n2 = idx >> 8, k2 = idx & 255;  // n2 0..511, k2 0..255: full 512x256
  int orig = ((n2 & 3) << 7) | (n2 >> 2);
  WcT[n2 * 256 + k2] = f2bf(Wc[k2 * 512 + orig]);
}

__global__ void k_deg(const int* __restrict__ ei, const float* __restrict__ ea,
                      float* __restrict__ deg, int* __restrict__ counts) {
  int e = blockIdx.x * 256 + threadIdx.x;
  if (e >= N_EDGES) return;
  int d = ei[N_EDGES + e];
  atomicAdd(&deg[d], ea[e]);
  atomicAdd(&counts[d], 1);
}

// single-block scan: counts -> exclusive row_ptr/cursor; dinv = rsqrt(deg).
// Vectorized int4/float4 loads (N_NODES = 1000*20 exactly; threads >= 1000
// own nothing), shfl wave-scan (2 barriers total), vectorized stores.
__global__ __launch_bounds__(1024) void k_scan(
    const int* __restrict__ counts, const float* __restrict__ deg,
    float* __restrict__ dinv, int* __restrict__ row_ptr,
    int* __restrict__ cursor) {
  __shared__ int smw[16];
  int t = threadIdx.x;
  int lane = t & 63, wv = t >> 6;
  int base = t * 20;
  int v[20];
  float dv[20];
  bool live = (t < 1000);
  if (live) {
    const int4* pc = (const int4*)(counts + base);
    const float4* pd = (const float4*)(deg + base);
#pragma unroll
    for (int i = 0; i < 5; ++i) {
      int4 q = pc[i];
      float4 f = pd[i];
      v[4 * i] = q.x; v[4 * i + 1] = q.y; v[4 * i + 2] = q.z; v[4 * i + 3] = q.w;
      dv[4 * i] = f.x; dv[4 * i + 1] = f.y; dv[4 * i + 2] = f.z; dv[4 * i + 3] = f.w;
    }
  } else {
#pragma unroll
    for (int i = 0; i < 20; ++i) { v[i] = 0; dv[i] = 1.f; }
  }
  int s = 0;
#pragma unroll
  for (int i = 0; i < 20; ++i) s += v[i];
  // wave-level inclusive scan of per-thread sums
  int inc = s;
#pragma unroll
  for (int o = 1; o < 64; o <<= 1) {
    int u = __shfl_up(inc, o);
    if (lane >= o) inc += u;
  }
  if (lane == 63) smw[wv] = inc;
  __syncthreads();
  if (t == 0) {
    int r = 0;
#pragma unroll
    for (int i = 0; i < 16; ++i) { int x = smw[i]; smw[i] = r; r += x; }
  }
  __syncthreads();
  int run = smw[wv] + inc - s;  // exclusive prefix of this thread's chunk
  if (live) {
    int rp[20];
    float iv[20];
#pragma unroll
    for (int i = 0; i < 20; ++i) {
      rp[i] = run;
      run += v[i];
      iv[i] = rsqrtf(dv[i]);
    }
    int4* prp = (int4*)(row_ptr + base);
    int4* pcu = (int4*)(cursor + base);
    float4* pdv = (float4*)(dinv + base);
#pragma unroll
    for (int i = 0; i < 5; ++i) {
      int4 q; q.x = rp[4 * i]; q.y = rp[4 * i + 1]; q.z = rp[4 * i + 2]; q.w = rp[4 * i + 3];
      prp[i] = q;
      pcu[i] = q;
      float4 f; f.x = iv[4 * i]; f.y = iv[4 * i + 1]; f.z = iv[4 * i + 2]; f.w = iv[4 * i + 3];
      pdv[i] = f;
    }
  }
  if (t == 0) row_ptr[N_NODES] = N_EDGES;
}

// csr packed as int2 {src, bitcast(weight)}
__global__ void k_fill(const int* __restrict__ ei, const float* __restrict__ ea,
                       const float* __restrict__ dinv, int* __restrict__ cursor,
                       int2* __restrict__ csr) {
  int e = blockIdx.x * 256 + threadIdx.x;
  if (e >= N_EDGES) return;
  int s = ei[e], d = ei[N_EDGES + e];
  int k = atomicAdd(&cursor[d], 1);
  int2 p;
  p.x = s;
  p.y = __builtin_bit_cast(int, dinv[s] * ea[e] * dinv[d]);
  csr[k] = p;
}

// ---------------- aggregation (gather via CSR, one wave per node) -------------
// Edge records are lane-loaded (coalesced int2) and broadcast via __shfl so
// row gathers issue independently (MLP).

// init: gather fp32 h,c -> AhAc rows (256 bf16: cols 0..127 Ah, 128..255 Ac)
__global__ __launch_bounds__(256) void k_agg_init(
    const float* __restrict__ h, const float* __restrict__ c,
    unsigned int* __restrict__ AhAc_u, const float* __restrict__ dinv,
    const int* __restrict__ row_ptr, const int2* __restrict__ csr) {
  int wid = (blockIdx.x * 256 + threadIdx.x) >> 6;
  int lane = threadIdx.x & 63;
  if (wid >= N_NODES) return;
  float di = dinv[wid], dd = di * di;
  const float4* xb = (lane < 32) ? (const float4*)h : (const float4*)c;
  int lcol = lane & 31;
  float4 a = xb[(size_t)wid * 32 + lcol];
  float s0 = a.x * dd, s1 = a.y * dd, s2 = a.z * dd, s3 = a.w * dd;
  int e0 = row_ptr[wid], end = row_ptr[wid + 1];
  for (int base = e0; base < end; base += 64) {
    int n = end - base;
    if (n > 64) n = 64;
    int sl = 0;
    float wl = 0.f;
    if (base + lane < end) {
      int2 p = csr[base + lane];
      sl = p.x;
      wl = __builtin_bit_cast(float, p.y);
    }
    int j = 0;
    for (; j + 4 <= n; j += 4) {
      int sa = __shfl(sl, j), sb = __shfl(sl, j + 1);
      int sc = __shfl(sl, j + 2), sd = __shfl(sl, j + 3);
      float wa = __shfl(wl, j), wb = __shfl(wl, j + 1);
      float wc = __shfl(wl, j + 2), wd = __shfl(wl, j + 3);
      float4 va = xb[(size_t)sa * 32 + lcol];
      float4 vb = xb[(size_t)sb * 32 + lcol];
      float4 vc = xb[(size_t)sc * 32 + lcol];
      float4 vd = xb[(size_t)sd * 32 + lcol];
      s0 += va.x * wa; s1 += va.y * wa; s2 += va.z * wa; s3 += va.w * wa;
      s0 += vb.x * wb; s1 += vb.y * wb; s2 += vb.z * wb; s3 += vb.w * wb;
      s0 += vc.x * wc; s1 += vc.y * wc; s2 += vc.z * wc; s3 += vc.w * wc;
      s0 += vd.x * wd; s1 += vd.y * wd; s2 += vd.z * wd; s3 += vd.w * wd;
    }
    for (; j < n; ++j) {
      int sa = __shfl(sl, j);
      float wa = __shfl(wl, j);
      float4 va = xb[(size_t)sa * 32 + lcol];
      s0 += va.x * wa; s1 += va.y * wa; s2 += va.z * wa; s3 += va.w * wa;
    }
  }
  uint2 o;
  o.x = (unsigned int)f2bf(s0) | ((unsigned int)f2bf(s1) << 16);
  o.y = (unsigned int)f2bf(s2) | ((unsigned int)f2bf(s3) << 16);
  ((uint2*)AhAc_u)[(size_t)wid * 64 + lane] = o;
}

// step: gather hbf rows (128 bf16) -> write into AhAc cols 128..255 (Aht),
// so the step GEMM reads A = [Ah | Aht] with K=256 (Kbuf GEMM folded in).
__global__ __launch_bounds__(256) void k_agg_step(
    const unsigned int* __restrict__ hbf_u, unsigned int* __restrict__ AhAc_u,
    const float* __restrict__ dinv, const int* __restrict__ row_ptr,
    const int2* __restrict__ csr) {
  int wid = (blockIdx.x * 256 + threadIdx.x) >> 6;
  int lane = threadIdx.x & 63;
  if (wid >= N_NODES) return;
  float di = dinv[wid], dd = di * di;
  unsigned int a = hbf_u[(size_t)wid * 64 + lane];
  float s0 = bflo(a) * dd, s1 = bfhi(a) * dd;
  int e0 = row_ptr[wid], end = row_ptr[wid + 1];
  for (int base = e0; base < end; base += 64) {
    int n = end - base;
    if (n > 64) n = 64;
    int sl = 0;
    float wl = 0.f;
    if (base + lane < end) {
      int2 p = csr[base + lane];
      sl = p.x;
      wl = __builtin_bit_cast(float, p.y);
    }
    int j = 0;
    for (; j + 4 <= n; j += 4) {
      int sa = __shfl(sl, j), sb = __shfl(sl, j + 1);
      int sc = __shfl(sl, j + 2), sd = __shfl(sl, j + 3);
      float wa = __shfl(wl, j), wb = __shfl(wl, j + 1);
      float wc = __shfl(wl, j + 2), wd = __shfl(wl, j + 3);
      unsigned int va = hbf_u[(size_t)sa * 64 + lane];
      unsigned int vb = hbf_u[(size_t)sb * 64 + lane];
      unsigned int vc = hbf_u[(size_t)sc * 64 + lane];
      unsigned int vd = hbf_u[(size_t)sd * 64 + lane];
      s0 += bflo(va) * wa; s1 += bfhi(va) * wa;
      s0 += bflo(vb) * wb; s1 += bfhi(vb) * wb;
      s0 += bflo(vc) * wc; s1 += bfhi(vc) * wc;
      s0 += bflo(vd) * wd; s1 += bfhi(vd) * wd;
    }
    for (; j < n; ++j) {
      int sa = __shfl(sl, j);
      float wa = __shfl(wl, j);
      unsigned int va = hbf_u[(size_t)sa * 64 + lane];
      s0 += bflo(va) * wa; s1 += bfhi(va) * wa;
    }
  }
  AhAc_u[(size_t)wid * 128 + 64 + lane] =
      (unsigned int)f2bf(s0) | ((unsigned int)f2bf(s1) << 16);
}

// ---------------- bf16 MFMA GEMM with global_load_lds + XOR-swizzled LDS -----
// C[128x128] = A[128xKK](row-stride LDA) @ BT[128 of KK]^T + epilogue.
// EPI 0 (init, KK=256): v += bias[gcol]; elu; col<128 -> hbf else c_cur.
// EPI 2 (step, KK=256): gates fused; gi..gg = acc + bcp[gcol] (bias).
template <int EPI, int KK, int LDA>
__global__ __launch_bounds__(256) void k_gemm(
    const unsigned short* __restrict__ A, const unsigned short* __restrict__ BT,
    const float* __restrict__ bias,
    float* __restrict__ c_cur, unsigned short* __restrict__ hbf,
    float* __restrict__ out0) {
  __shared__ __align__(16) union {
    struct { unsigned short a[128 * 64]; unsigned short b[128 * 64]; } ab;
    float ep[64 * 132];
  } sm;
  const int M = N_NODES;
  int tid = threadIdx.x;
  int bm0 = blockIdx.x * 128, bn0 = blockIdx.y * 128;
  int wave = tid >> 6, lane = tid & 63;
  int wrow = (wave >> 1) * 64, wcol = (wave & 1) * 64;
  int lr = lane & 15, lq = lane >> 4;
  int key = lr & 7;

  // staging lane roles: 8 lanes/row, 8 rows/wave/call
  int lr8 = lane >> 3, cq = lane & 7;
  int gq8 = (cq ^ lr8) * 8;  // swizzled global chunk offset (shorts)

  floatx4 acc[4][4];
#pragma unroll
  for (int i = 0; i < 4; i++)
#pragma unroll
    for (int j = 0; j < 4; j++) acc[i][j] = (floatx4){0.f, 0.f, 0.f, 0.f};

  for (int k0 = 0; k0 < KK; k0 += 64) {
    __syncthreads();
#pragma unroll
    for (int p = 0; p < 4; ++p) {
      int row = p * 32 + wave * 8;        // wave-uniform base row
      int ra = bm0 + row + lr8;
      if (ra > M - 1) ra = M - 1;         // clamp: junk rows never stored
      gl_lds16(A + (size_t)ra * LDA + k0 + gq8, sm.ab.a + row * 64);
      gl_lds16(BT + (size_t)(bn0 + row + lr8) * KK + k0 + gq8,
               sm.ab.b + row * 64);
    }
    __syncthreads();
#pragma unroll
    for (int ks = 0; ks < 2; ++ks) {
      int q = ks * 4 + lq;
      int slot = (q ^ key) << 3;
      bf16x8 af[4], bfr[4];
#pragma unroll
      for (int mi = 0; mi < 4; mi++)
        af[mi] = *(const bf16x8*)(sm.ab.a + (wrow + mi * 16 + lr) * 64 + slot);
#pragma unroll
      for (int ni = 0; ni < 4; ni++)
        bfr[ni] = *(const bf16x8*)(sm.ab.b + (wcol + ni * 16 + lr) * 64 + slot);
#pragma unroll
      for (int mi = 0; mi < 4; mi++)
#pragma unroll
        for (int ni = 0; ni < 4; ni++)
          acc[mi][ni] = __builtin_amdgcn_mfma_f32_16x16x32_bf16(
              af[mi], bfr[ni], acc[mi][ni], 0, 0, 0);
    }
  }
  __syncthreads();  // sm.ab dead before epilogue reuse

  if (EPI == 0) {
#pragma unroll
    for (int mi = 0; mi < 4; mi++) {
#pragma unroll
      for (int r = 0; r < 4; r++) {
        int grow = bm0 + wrow + mi * 16 + lq * 4 + r;
        if (grow >= M) continue;
#pragma unroll
        for (int ni = 0; ni < 4; ni++) {
          int gcol = bn0 + wcol + ni * 16 + lr;
          float v = acc[mi][ni][r] + bias[gcol];
          v = (v > 0.f) ? v : expm1f(v);
          if (gcol < 128) hbf[(size_t)grow * 128 + gcol] = f2bf(v);
          else c_cur[(size_t)grow * 128 + gcol - 128] = v;
        }
      }
    }
  } else {
    // two 64-row chunks through LDS transpose; fused LSTM gates
#pragma unroll
    for (int hch = 0; hch < 2; ++hch) {
      if ((wrow >> 6) == hch) {
#pragma unroll
        for (int mi = 0; mi < 4; mi++)
#pragma unroll
          for (int r = 0; r < 4; r++) {
            int row_l = mi * 16 + lq * 4 + r;
#pragma unroll
            for (int ni = 0; ni < 4; ni++)
              sm.ep[row_l * 132 + wcol + ni * 16 + lr] = acc[mi][ni][r];
          }
      }
      __syncthreads();
#pragma unroll
      for (int it = 0; it < 8; ++it) {
        int p = tid + it * 256;
        int row_l = p >> 5, j = p & 31;
        int grow = bm0 + hch * 64 + row_l;
        if (grow < M) {
          int jg = (bn0 >> 2) + j;
          const float* eb = sm.ep + row_l * 132 + 4 * j;
          float4 kb = *(const float4*)&bias[bn0 + 4 * j];  // bcp (gate-interleaved bias)
          float gi = eb[0] + kb.x;
          float gf = eb[1] + kb.y;
          float go = eb[2] + kb.z;
          float gg = eb[3] + kb.w;
          size_t o = (size_t)grow * 128 + jg;
          float cp = c_cur[o];
          float cn = sigf(gf) * cp + sigf(gi) * tanhf(gg);
          float hn = sigf(go) * tanhf(cn);
          c_cur[o] = cn;
          hbf[o] = f2bf(hn);
          out0[o] = hn;
        }
      }
      __syncthreads();
    }
  }
}

// ---------------- host launcher ----------------
extern "C" void kernel_launch(void* const* d_in, const int* in_sizes, int n_in,
                              void* d_out, int out_size, void* d_ws, size_t ws_size,
                              hipStream_t stream) {
  const float* h  = (const float*)d_in[0];
  const float* c  = (const float*)d_in[1];
  const int*   ei = (const int*)d_in[2];
  const float* ea = (const float*)d_in[3];
  const float* Wi = (const float*)d_in[4];
  const float* bi = (const float*)d_in[5];
  const float* Wc = (const float*)d_in[6];
  const float* bc = (const float*)d_in[7];
  float* out = (float*)d_out;

  char* w = (char*)d_ws;
  size_t off = 0;
  auto alloc = [&](size_t bytes) {
    void* p = w + off;
    off += (bytes + 511) & ~(size_t)511;
    return p;
  };
  float* deg           = (float*)alloc(N_NODES * 4);
  float* dinv          = (float*)alloc(N_NODES * 4);
  int* counts          = (int*)alloc(N_NODES * 4);
  int* cursor          = (int*)alloc(N_NODES * 4);
  int* row_ptr         = (int*)alloc((N_NODES + 1) * 4);
  int2* csr            = (int2*)alloc((size_t)N_EDGES * 8);
  unsigned short* WiT  = (unsigned short*)alloc(256 * 256 * 2);
  unsigned short* WcT  = (unsigned short*)alloc(512 * 256 * 2);
  float* bcp           = (float*)alloc(512 * 4);
  unsigned short* AhAc = (unsigned short*)alloc((size_t)N_NODES * 256 * 2);
  unsigned short* hbf  = (unsigned short*)alloc((size_t)N_NODES * 128 * 2);
  float* c_cur         = (float*)alloc((size_t)N_NODES * 128 * 4);

  const int NB_E = (N_EDGES + 255) / 256;  // 1250
  const int NB_AGG = N_NODES * 64 / 256;   // 5000
  const int MB = (N_NODES + 127) / 128;    // 157

  k_prologue<<<512, 256, 0, stream>>>(Wi, Wc, bc, WiT, WcT, bcp, deg, counts);
  k_deg<<<NB_E, 256, 0, stream>>>(ei, ea, deg, counts);
  k_scan<<<1, 1024, 0, stream>>>(counts, deg, dinv, row_ptr, cursor);
  k_fill<<<NB_E, 256, 0, stream>>>(ei, ea, dinv, cursor, csr);

  k_agg_init<<<NB_AGG, 256, 0, stream>>>(h, c, (unsigned int*)AhAc, dinv,
                                         row_ptr, csr);
  // states = elu([Ah|Ac]@Wi + bi) -> hbf, c_cur
  k_gemm<0, 256, 256><<<dim3(MB, 2), 256, 0, stream>>>(
      AhAc, WiT, bi, c_cur, hbf, nullptr);

  for (int t = 0; t < SEQ; ++t) {
    // Aht written into AhAc cols 128..255; gates = [Ah|Aht] @ [W1;W2] + bcp
    k_agg_step<<<NB_AGG, 256, 0, stream>>>((unsigned int*)hbf,
                                           (unsigned int*)AhAc, dinv, row_ptr,
                                           csr);
    k_gemm<2, 256, 256><<<dim3(MB, 4), 256, 0, stream>>>(
        AhAc, WcT, bcp, c_cur, hbf, out + (size_t)t * N_NODES * 128);
  }
}